// Round 1
// baseline (322.091 us; speedup 1.0000x reference)
//
#include <hip/hip_runtime.h>

#define S_LEN 2048
#define NHEAD 16
#define DHEAD 64
#define DMODEL 1024
#define BATCH 4

typedef short bf16x8 __attribute__((ext_vector_type(8)));
typedef float f32x4 __attribute__((ext_vector_type(4)));
typedef unsigned short u16;
typedef unsigned short u16x8 __attribute__((ext_vector_type(8)));
typedef unsigned short u16x4 __attribute__((ext_vector_type(4)));
typedef unsigned long long u64;

__device__ __forceinline__ u16 f2b(float f) {
  unsigned u = __builtin_bit_cast(unsigned, f);
  u += 0x7FFFu + ((u >> 16) & 1u);   // RTNE
  return (u16)(u >> 16);
}
__device__ __forceinline__ float b2f(u16 v) {
  unsigned u = ((unsigned)v) << 16;
  return __builtin_bit_cast(float, u);
}
__device__ __forceinline__ f32x4 mfma16(bf16x8 a, bf16x8 b, f32x4 c) {
  return __builtin_amdgcn_mfma_f32_16x16x32_bf16(a, b, c, 0, 0, 0);
}
__device__ __forceinline__ void load_lds16(const void* g, void* l) {
  __builtin_amdgcn_global_load_lds(
      (const __attribute__((address_space(1))) unsigned int*)g,
      (__attribute__((address_space(3))) unsigned int*)l, 16, 0, 0);
}

// ---------------- prepass kernels ----------------

__global__ void cvt_f32_bf16(const float* __restrict__ src, u16* __restrict__ dst, int n4) {
  int i = blockIdx.x * 256 + threadIdx.x;
  int stride = gridDim.x * 256;
  for (; i < n4; i += stride) {
    float4 v = ((const float4*)src)[i];
    u16x4 o = { f2b(v.x), f2b(v.y), f2b(v.z), f2b(v.w) };
    ((u16x4*)dst)[i] = o;
  }
}

// W [16][1024][64] f32 -> WT [1024 c][1024 d] bf16, c = n*64+h
__global__ void repack_w(const float* __restrict__ W, u16* __restrict__ WT) {
  __shared__ u16 t[64][66];
  const int tid = threadIdx.x;
  const int n = blockIdx.y, d0 = blockIdx.x * 64;
  const float* src = W + (size_t)n * 65536;
  for (int p = 0; p < 4; ++p) {
    int idx = p * 256 + tid;
    int r = idx >> 4, cs = idx & 15;       // r = d-local, cs*4 = h-local
    float4 v = *(const float4*)(src + (size_t)(d0 + r) * 64 + cs * 4);
    t[r][cs*4+0] = f2b(v.x); t[r][cs*4+1] = f2b(v.y);
    t[r][cs*4+2] = f2b(v.z); t[r][cs*4+3] = f2b(v.w);
  }
  __syncthreads();
  for (int p = 0; p < 2; ++p) {
    int idx = p * 256 + tid;
    int hl = idx >> 3, ds = idx & 7;
    u16x8 o;
    for (int e = 0; e < 8; ++e) o[e] = t[ds*8+e][hl];
    *(u16x8*)(WT + (size_t)(n*64 + hl) * 1024 + d0 + ds*8) = o;
  }
}

// W_O [1024 c][1024 d] f32 -> WoT hi/lo [1024 d][1024 c] bf16
__global__ void split_wo(const float* __restrict__ Wo, u16* __restrict__ Hi, u16* __restrict__ Lo) {
  __shared__ u16 th[64][66];
  __shared__ u16 tl[64][66];
  const int tid = threadIdx.x;
  const int d0 = blockIdx.x * 64, c0 = blockIdx.y * 64;
  for (int p = 0; p < 4; ++p) {
    int idx = p * 256 + tid;
    int r = idx >> 4, cs = idx & 15;       // r = c-local
    float4 v = *(const float4*)(Wo + (size_t)(c0 + r) * 1024 + d0 + cs * 4);
    float f[4] = {v.x, v.y, v.z, v.w};
    for (int e = 0; e < 4; ++e) {
      u16 hb = f2b(f[e]);
      th[r][cs*4+e] = hb;
      tl[r][cs*4+e] = f2b(f[e] - b2f(hb));
    }
  }
  __syncthreads();
  for (int p = 0; p < 2; ++p) {
    int idx = p * 256 + tid;
    int dr = idx >> 3, cs = idx & 7;
    u16x8 oh, ol;
    for (int e = 0; e < 8; ++e) { oh[e] = th[cs*8+e][dr]; ol[e] = tl[cs*8+e][dr]; }
    *(u16x8*)(Hi + (size_t)(d0 + dr) * 1024 + c0 + cs*8) = oh;
    *(u16x8*)(Lo + (size_t)(d0 + dr) * 1024 + c0 + cs*8) = ol;
  }
}

// mask [2048 q][2048 k] int32 -> MT [2048 k][2048 q] bf16 bias {0, -99840}
__global__ void mask_transpose(const int* __restrict__ M, u16* __restrict__ MT) {
  __shared__ u16 t[64][66];
  const int tid = threadIdx.x;
  const int q0 = blockIdx.x * 64, k0 = blockIdx.y * 64;
  for (int p = 0; p < 4; ++p) {
    int idx = p * 256 + tid;
    int r = idx >> 4, cs = idx & 15;       // r = q-local
    int4 v = *(const int4*)(M + (size_t)(q0 + r) * 2048 + k0 + cs * 4);
    t[r][cs*4+0] = v.x ? 0xC7C3 : 0;       // bf16(-99840)
    t[r][cs*4+1] = v.y ? 0xC7C3 : 0;
    t[r][cs*4+2] = v.z ? 0xC7C3 : 0;
    t[r][cs*4+3] = v.w ? 0xC7C3 : 0;
  }
  __syncthreads();
  for (int p = 0; p < 2; ++p) {
    int idx = p * 256 + tid;
    int kr = idx >> 3, qs = idx & 7;
    u16x8 o;
    for (int e = 0; e < 8; ++e) o[e] = t[qs*8+e][kr];
    *(u16x8*)(MT + (size_t)(k0 + kr) * 2048 + q0 + qs*8) = o;
  }
}

// v [8192][1024] bf16 -> VT [(b*16+h)*64 + dh][2048 s] bf16
__global__ void transpose_v(const u16* __restrict__ V, u16* __restrict__ VT) {
  __shared__ u16 t[64][66];
  const int tid = threadIdx.x;
  const int s0 = blockIdx.x * 64;
  const int b = blockIdx.y >> 4, h = blockIdx.y & 15;
  for (int p = 0; p < 2; ++p) {
    int idx = p * 256 + tid;
    int r = idx >> 3, sg = idx & 7;        // r = s-local
    u16x8 v = *(const u16x8*)(V + (size_t)(b*S_LEN + s0 + r) * 1024 + h*64 + sg*8);
    for (int e = 0; e < 8; ++e) t[r][sg*8+e] = v[e];
  }
  __syncthreads();
  for (int p = 0; p < 2; ++p) {
    int idx = p * 256 + tid;
    int dr = idx >> 3, ss = idx & 7;       // dr = dh
    u16x8 o;
    for (int e = 0; e < 8; ++e) o[e] = t[ss*8+e][dr];
    *(u16x8*)(VT + ((size_t)(b*NHEAD + h) * 64 + dr) * 2048 + s0 + ss*8) = o;
  }
}

// ---------------- GEMM: C[M][1024] = A[M][1024] * Bt[1024][1024]^T + bias ----------------

template<int BF16OUT>
__global__ __launch_bounds__(256, 2)
void gemm_bt(const u16* __restrict__ A, const u16* __restrict__ Bt,
             const float* __restrict__ bias, void* __restrict__ Cout)
{
  __shared__ __align__(16) char As[16384];
  __shared__ __align__(16) char Bs[16384];
  const int tid = threadIdx.x, wid = tid >> 6, lane = tid & 63;
  const int lq = lane & 15, g = lane >> 4;
  const size_t am0 = (size_t)blockIdx.y * 128;
  const size_t bn0 = (size_t)blockIdx.x * 128;
  const int wr = (wid >> 1) * 64, wc = (wid & 1) * 64;
  f32x4 z4 = {0.f, 0.f, 0.f, 0.f};
  f32x4 acc[4][4];
  for (int i = 0; i < 4; ++i) for (int j = 0; j < 4; ++j) acc[i][j] = z4;
  for (int k0 = 0; k0 < DMODEL; k0 += 64) {
#pragma unroll
    for (int c = 0; c < 4; ++c) {
      int idx = c*256 + tid, r = idx >> 3, s = idx & 7;
      load_lds16(A + (am0 + r)*DMODEL + k0 + ((s ^ (r & 7)) << 3), As + idx*16);
    }
#pragma unroll
    for (int c = 0; c < 4; ++c) {
      int idx = c*256 + tid, r = idx >> 3, s = idx & 7;
      load_lds16(Bt + (bn0 + r)*DMODEL + k0 + ((s ^ (r & 7)) << 3), Bs + idx*16);
    }
    __syncthreads();
#pragma unroll
    for (int ks = 0; ks < 2; ++ks) {
      bf16x8 af[4], bfr[4];
#pragma unroll
      for (int i = 0; i < 4; ++i) {
        int row = wr + i*16 + lq;
        af[i] = *(const bf16x8*)(As + row*128 + (((ks*4 + g) ^ (row & 7)) << 4));
      }
#pragma unroll
      for (int j = 0; j < 4; ++j) {
        int row = wc + j*16 + lq;
        bfr[j] = *(const bf16x8*)(Bs + row*128 + (((ks*4 + g) ^ (row & 7)) << 4));
      }
#pragma unroll
      for (int i = 0; i < 4; ++i)
#pragma unroll
        for (int j = 0; j < 4; ++j)
          acc[i][j] = mfma16(af[i], bfr[j], acc[i][j]);
    }
    __syncthreads();
  }
#pragma unroll
  for (int i = 0; i < 4; ++i)
#pragma unroll
    for (int j = 0; j < 4; ++j) {
      size_t row = am0 + wr + i*16 + g*4;
      int col = (int)bn0 + wc + j*16 + lq;
      float bv = bias[col];
#pragma unroll
      for (int r = 0; r < 4; ++r) {
        float v = acc[i][j][r] + bv;
        if (BF16OUT) ((u16*)Cout)[(row + r)*DMODEL + col] = f2b(v);
        else         ((float*)Cout)[(row + r)*DMODEL + col] = v;
      }
    }
}

// ---------------- out = Z(f32, split hi/lo) @ WoT^T + b_O ----------------

__global__ __launch_bounds__(256, 2)
void gemm_out(const float* __restrict__ Z, const u16* __restrict__ Bh,
              const u16* __restrict__ Bl, const float* __restrict__ bias,
              float* __restrict__ Cout)
{
  __shared__ __align__(16) char Ah[16384];
  __shared__ __align__(16) char Al[16384];
  __shared__ __align__(16) char Bhs[16384];
  __shared__ __align__(16) char Bls[16384];
  const int tid = threadIdx.x, wid = tid >> 6, lane = tid & 63;
  const int lq = lane & 15, g = lane >> 4;
  const size_t am0 = (size_t)blockIdx.y * 128;
  const size_t bn0 = (size_t)blockIdx.x * 128;
  const int wr = (wid >> 1) * 64, wc = (wid & 1) * 64;
  f32x4 z4 = {0.f, 0.f, 0.f, 0.f};
  f32x4 acc[4][4];
  for (int i = 0; i < 4; ++i) for (int j = 0; j < 4; ++j) acc[i][j] = z4;
  for (int k0 = 0; k0 < DMODEL; k0 += 64) {
#pragma unroll
    for (int c = 0; c < 8; ++c) {
      int idx = c*256 + tid, r = idx >> 4, fs = idx & 15;
      float4 v = *(const float4*)(Z + (am0 + r)*DMODEL + k0 + fs*4);
      float f[4] = {v.x, v.y, v.z, v.w};
      u16x4 hv, lv;
      for (int e = 0; e < 4; ++e) {
        u16 hb = f2b(f[e]);
        hv[e] = hb;
        lv[e] = f2b(f[e] - b2f(hb));
      }
      int byo = r*128 + ((((fs >> 1) ^ (r & 7)) << 4) | ((fs & 1) << 3));
      *(u16x4*)(Ah + byo) = hv;
      *(u16x4*)(Al + byo) = lv;
    }
#pragma unroll
    for (int c = 0; c < 4; ++c) {
      int idx = c*256 + tid, r = idx >> 3, s = idx & 7;
      load_lds16(Bh + (bn0 + r)*DMODEL + k0 + ((s ^ (r & 7)) << 3), Bhs + idx*16);
    }
#pragma unroll
    for (int c = 0; c < 4; ++c) {
      int idx = c*256 + tid, r = idx >> 3, s = idx & 7;
      load_lds16(Bl + (bn0 + r)*DMODEL + k0 + ((s ^ (r & 7)) << 3), Bls + idx*16);
    }
    __syncthreads();
#pragma unroll
    for (int ks = 0; ks < 2; ++ks) {
      bf16x8 ah[4], al[4], bh4[4], bl4[4];
#pragma unroll
      for (int i = 0; i < 4; ++i) {
        int row = wr + i*16 + lq;
        int off = row*128 + (((ks*4 + g) ^ (row & 7)) << 4);
        ah[i] = *(const bf16x8*)(Ah + off);
        al[i] = *(const bf16x8*)(Al + off);
      }
#pragma unroll
      for (int j = 0; j < 4; ++j) {
        int row = wc + j*16 + lq;
        int off = row*128 + (((ks*4 + g) ^ (row & 7)) << 4);
        bh4[j] = *(const bf16x8*)(Bhs + off);
        bl4[j] = *(const bf16x8*)(Bls + off);
      }
#pragma unroll
      for (int i = 0; i < 4; ++i)
#pragma unroll
        for (int j = 0; j < 4; ++j) {
          acc[i][j] = mfma16(al[i], bh4[j], acc[i][j]);
          acc[i][j] = mfma16(ah[i], bl4[j], acc[i][j]);
          acc[i][j] = mfma16(ah[i], bh4[j], acc[i][j]);
        }
    }
    __syncthreads();
  }
#pragma unroll
  for (int i = 0; i < 4; ++i)
#pragma unroll
    for (int j = 0; j < 4; ++j) {
      size_t row = am0 + wr + i*16 + g*4;
      int col = (int)bn0 + wc + j*16 + lq;
      float bv = bias[col];
#pragma unroll
      for (int r = 0; r < 4; ++r)
        Cout[(row + r)*DMODEL + col] = acc[i][j][r] + bv;
    }
}

// ---------------- flash attention ----------------
// grid (32 q-tiles, 16 heads, 4 batch), 256 threads (4 waves x 16 q-rows)
__global__ __launch_bounds__(256, 2)
void attn(const u16* __restrict__ Q, const u16* __restrict__ K,
          const u16* __restrict__ VT, const u16* __restrict__ MT,
          float* __restrict__ Zf)
{
  __shared__ __align__(16) char Kl[8192];   // [kv 64][dh 64] bf16, 16B-slot xor-swizzled
  __shared__ __align__(16) char Vl[8192];   // [dh 64][kv 64] bf16, swizzled
  __shared__ __align__(16) char Pl[8192];   // per-wave [q 16][kv 64] bf16, 8B-slot swizzled
  const int tid = threadIdx.x, wid = tid >> 6, lane = tid & 63;
  const int lq = lane & 15, g = lane >> 4;
  const int q0 = blockIdx.x * 64, h = blockIdx.y, b = blockIdx.z;
  const int qw = q0 + wid * 16;

  bf16x8 qf[2];
  {
    const u16* qp = Q + (size_t)(b*S_LEN + qw + lq) * DMODEL + h*DHEAD + g*8;
    qf[0] = *(const bf16x8*)qp;
    qf[1] = *(const bf16x8*)(qp + 32);
  }
  f32x4 z4 = {0.f, 0.f, 0.f, 0.f};
  f32x4 Oc[4];
  for (int t = 0; t < 4; ++t) Oc[t] = z4;
  float mrow = -1e30f, lrow = 0.f;

  const size_t kbase = (size_t)(b*S_LEN)*DMODEL + h*DHEAD;
  const size_t vbase = (size_t)((b*NHEAD + h)*DHEAD)*S_LEN;
  const u16* mtp = MT + q0 + wid*16 + lq;
  char* myP = Pl + wid*2048;

  for (int it = 0; it < 32; ++it) {
    const int kv0 = it * 64;
#pragma unroll
    for (int c = 0; c < 2; ++c) {
      int idx = c*256 + tid, r = idx >> 3, s = idx & 7;
      load_lds16(K + kbase + (size_t)(kv0 + r)*DMODEL + ((s ^ (r & 7)) << 3), Kl + idx*16);
    }
#pragma unroll
    for (int c = 0; c < 2; ++c) {
      int idx = c*256 + tid, r = idx >> 3, s = idx & 7;
      load_lds16(VT + vbase + (size_t)r*S_LEN + kv0 + ((s ^ (r & 7)) << 3), Vl + idx*16);
    }
    __syncthreads();

    // S^T = K @ Q^T : tile t rows kv=t*16+4g+r, col q=lq
    f32x4 st[4];
#pragma unroll
    for (int t = 0; t < 4; ++t) {
      f32x4 a = z4;
#pragma unroll
      for (int hh = 0; hh < 2; ++hh) {
        int row = t*16 + lq;
        bf16x8 kf = *(const bf16x8*)(Kl + row*128 + (((hh*4 + g) ^ (row & 7)) << 4));
        a = mfma16(kf, qf[hh], a);
      }
      st[t] = a;
    }

    float sv[16];
    float pmax = -1e30f;
#pragma unroll
    for (int t = 0; t < 4; ++t)
#pragma unroll
      for (int r = 0; r < 4; ++r) {
        float bias = b2f(mtp[(size_t)(kv0 + t*16 + g*4 + r) * S_LEN]);
        float x = st[t][r] * 0.125f + bias;
        sv[t*4 + r] = x;
        pmax = fmaxf(pmax, x);
      }
    pmax = fmaxf(pmax, __shfl_xor(pmax, 16));
    pmax = fmaxf(pmax, __shfl_xor(pmax, 32));
    float mnew = fmaxf(mrow, pmax);
    float psum = 0.f;
#pragma unroll
    for (int t = 0; t < 4; ++t) {
      u64 w = 0;
#pragma unroll
      for (int r = 0; r < 4; ++r) {
        float p = __expf(sv[t*4 + r] - mnew);
        psum += p;
        w |= (u64)f2b(p) << (16*r);
      }
      *(u64*)(myP + lq*128 + (((4*t + g) ^ lq) << 3)) = w;
    }
    psum += __shfl_xor(psum, 16);
    psum += __shfl_xor(psum, 32);
    float fac = __expf(mrow - mnew);
    lrow = lrow * fac + psum;
    mrow = mnew;
    float fr0 = __shfl(fac, g*4 + 0);
    float fr1 = __shfl(fac, g*4 + 1);
    float fr2 = __shfl(fac, g*4 + 2);
    float fr3 = __shfl(fac, g*4 + 3);
#pragma unroll
    for (int t = 0; t < 4; ++t) {
      Oc[t][0] *= fr0; Oc[t][1] *= fr1; Oc[t][2] *= fr2; Oc[t][3] *= fr3;
    }
    asm volatile("s_waitcnt lgkmcnt(0)" ::: "memory");
    __builtin_amdgcn_sched_barrier(0);
    bf16x8 pf[2];
#pragma unroll
    for (int hh = 0; hh < 2; ++hh) {
      int s0 = hh*8 + g*2;
      u64 plo = *(const u64*)(myP + lq*128 + (((s0    ) ^ lq) << 3));
      u64 phi = *(const u64*)(myP + lq*128 + (((s0 + 1) ^ lq) << 3));
      union { u64 q[2]; bf16x8 v; } u;
      u.q[0] = plo; u.q[1] = phi;
      pf[hh] = u.v;
    }
#pragma unroll
    for (int t = 0; t < 4; ++t)
#pragma unroll
      for (int hh = 0; hh < 2; ++hh) {
        int row = t*16 + lq;
        bf16x8 vf = *(const bf16x8*)(Vl + row*128 + (((hh*4 + g) ^ (row & 7)) << 4));
        Oc[t] = mfma16(pf[hh], vf, Oc[t]);
      }
    __syncthreads();
  }
  float inv = 1.f / lrow;
  float ir0 = __shfl(inv, g*4+0), ir1 = __shfl(inv, g*4+1);
  float ir2 = __shfl(inv, g*4+2), ir3 = __shfl(inv, g*4+3);
#pragma unroll
  for (int t = 0; t < 4; ++t) {
    size_t base = ((size_t)(b*S_LEN + qw + g*4)*NHEAD + h)*DHEAD + t*16 + lq;
    Zf[base       ] = Oc[t][0]*ir0;
    Zf[base + 1024] = Oc[t][1]*ir1;
    Zf[base + 2048] = Oc[t][2]*ir2;
    Zf[base + 3072] = Oc[t][3]*ir3;
  }
}

// ---------------- launch ----------------

extern "C" void kernel_launch(void* const* d_in, const int* in_sizes, int n_in,
                              void* d_out, int out_size, void* d_ws, size_t ws_size,
                              hipStream_t stream) {
  const float* x_q  = (const float*)d_in[0];
  const float* x_kv = (const float*)d_in[1];
  const int*   mask = (const int*)d_in[2];
  const float* W_Q  = (const float*)d_in[3];
  const float* W_K  = (const float*)d_in[4];
  const float* W_V  = (const float*)d_in[5];
  const float* W_O  = (const float*)d_in[6];
  const float* b_Q  = (const float*)d_in[7];
  const float* b_K  = (const float*)d_in[8];
  const float* b_V  = (const float*)d_in[9];
  const float* b_O  = (const float*)d_in[10];

  if (ws_size < 102760448) return;  // need ~98 MB scratch

  u16* ws  = (u16*)d_ws;
  u16* XQ  = ws;                 // 8388608 elems (aliased by VT later)
  u16* XKV = XQ  + 8388608;
  u16* WQT = XKV + 8388608;      // 1048576 each
  u16* WKT = WQT + 1048576;
  u16* WVT = WKT + 1048576;
  u16* WOH = WVT + 1048576;
  u16* WOL = WOH + 1048576;
  u16* Qb  = WOL + 1048576;      // 8388608 each
  u16* Kb  = Qb  + 8388608;
  u16* Vb  = Kb  + 8388608;
  u16* MT  = Vb  + 8388608;      // 4194304
  u16* VTp = XQ;                 // alias: XQ dead after Q-GEMM

  float* out = (float*)d_out;
  float* zf  = out + 8388608;

  cvt_f32_bf16<<<2048, 256, 0, stream>>>(x_q,  XQ,  2097152);
  cvt_f32_bf16<<<2048, 256, 0, stream>>>(x_kv, XKV, 2097152);
  repack_w<<<dim3(16,16), 256, 0, stream>>>(W_Q, WQT);
  repack_w<<<dim3(16,16), 256, 0, stream>>>(W_K, WKT);
  repack_w<<<dim3(16,16), 256, 0, stream>>>(W_V, WVT);
  split_wo<<<dim3(16,16), 256, 0, stream>>>(W_O, WOH, WOL);
  mask_transpose<<<dim3(32,32), 256, 0, stream>>>(mask, MT);
  gemm_bt<1><<<dim3(8,64), 256, 0, stream>>>(XQ,  WQT, b_Q, Qb);
  gemm_bt<1><<<dim3(8,64), 256, 0, stream>>>(XKV, WKT, b_K, Kb);
  gemm_bt<1><<<dim3(8,64), 256, 0, stream>>>(XKV, WVT, b_V, Vb);
  transpose_v<<<dim3(32,64), 256, 0, stream>>>(Vb, VTp);
  attn<<<dim3(32,16,4), 256, 0, stream>>>(Qb, Kb, VTp, MT, zf);
  gemm_out<<<dim3(8,64), 256, 0, stream>>>(zf, WOH, WOL, b_O, out);
}